// Round 1
// baseline (27358.142 us; speedup 1.0000x reference)
//
#include <hip/hip_runtime.h>
#include <math.h>

#define S_LEN 4096
#define DMODEL 768
#define NHEAD 12
#define DHEAD 64
#define FFDIM 3072
#define NLAYER 12
#define WIN 256

// ---------------- LayerNorm helpers ----------------

__device__ inline void block_reduce2(float& sum, float& sq) {
    // 256 threads = 4 waves
    #pragma unroll
    for (int off = 32; off; off >>= 1) {
        sum += __shfl_xor(sum, off);
        sq  += __shfl_xor(sq, off);
    }
    __shared__ float red[8];
    int wid = threadIdx.x >> 6, lane = threadIdx.x & 63;
    if (lane == 0) { red[wid] = sum; red[wid + 4] = sq; }
    __syncthreads();
    sum = red[0] + red[1] + red[2] + red[3];
    sq  = red[4] + red[5] + red[6] + red[7];
    __syncthreads();
}

// x[row] = LN(in[row]) * s + b   (D=768, 256 threads, 3 elems/thread)
__global__ __launch_bounds__(256) void ln_kernel(const float* __restrict__ in,
                                                 const float* __restrict__ s,
                                                 const float* __restrict__ b,
                                                 float* __restrict__ out) {
    int row = blockIdx.x, tid = threadIdx.x;
    const float* p = in + (size_t)row * DMODEL;
    float v0 = p[tid], v1 = p[tid + 256], v2 = p[tid + 512];
    float sum = v0 + v1 + v2;
    float sq  = v0 * v0 + v1 * v1 + v2 * v2;
    block_reduce2(sum, sq);
    float mu = sum * (1.0f / DMODEL);
    float var = sq * (1.0f / DMODEL) - mu * mu;
    float rs = rsqrtf(var + 1e-5f);
    float* o = out + (size_t)row * DMODEL;
    o[tid]       = (v0 - mu) * rs * s[tid]       + b[tid];
    o[tid + 256] = (v1 - mu) * rs * s[tid + 256] + b[tid + 256];
    o[tid + 512] = (v2 - mu) * rs * s[tid + 512] + b[tid + 512];
}

// embedding gather + LN
__global__ __launch_bounds__(256) void embed_ln_kernel(const int* __restrict__ ids,
                                                       const float* __restrict__ wemb,
                                                       const float* __restrict__ pemb,
                                                       const float* __restrict__ s,
                                                       const float* __restrict__ b,
                                                       float* __restrict__ out) {
    int row = blockIdx.x, tid = threadIdx.x;
    int id = ids[row];
    const float* wp = wemb + (size_t)id * DMODEL;
    const float* pp = pemb + (size_t)(row + 2) * DMODEL;
    float v0 = wp[tid] + pp[tid];
    float v1 = wp[tid + 256] + pp[tid + 256];
    float v2 = wp[tid + 512] + pp[tid + 512];
    float sum = v0 + v1 + v2;
    float sq  = v0 * v0 + v1 * v1 + v2 * v2;
    block_reduce2(sum, sq);
    float mu = sum * (1.0f / DMODEL);
    float var = sq * (1.0f / DMODEL) - mu * mu;
    float rs = rsqrtf(var + 1e-5f);
    float* o = out + (size_t)row * DMODEL;
    o[tid]       = (v0 - mu) * rs * s[tid]       + b[tid];
    o[tid + 256] = (v1 - mu) * rs * s[tid + 256] + b[tid + 256];
    o[tid + 512] = (v2 - mu) * rs * s[tid + 512] + b[tid + 512];
}

// ---------------- GEMM: C = A@B + bias (+res) (+gelu) ----------------
// BM=128, BN=64, BK=16, 256 threads, 8x4 per thread.
// M%128==0, N%64==0, K%16==0 guaranteed by problem dims.
#define BM 128
#define BN 64
#define BK 16

__global__ __launch_bounds__(256) void gemm_kernel(const float* __restrict__ A,
                                                   const float* __restrict__ B,
                                                   const float* __restrict__ bias,
                                                   const float* __restrict__ res,
                                                   float* __restrict__ C,
                                                   int M, int N, int K, int act) {
    __shared__ float As[BK][BM];
    __shared__ float Bs[BK][BN];
    const int tid = threadIdx.x;
    const int bm = blockIdx.x * BM;
    const int bn = blockIdx.y * BN;
    const int tx = tid & 15;        // col group (4 cols)
    const int ty = tid >> 4;        // row group (8 rows)

    float acc[8][4] = {};

    // A-tile load mapping: 2 float4 / thread over [128][16] row-major
    const int arow = tid >> 2;            // 0..63
    const int acol = (tid & 3) * 4;       // 0,4,8,12
    // B-tile: 1 float4 / thread over [16][64]
    const int brow = tid >> 4;            // 0..15
    const int bcol = (tid & 15) * 4;      // 0..60

    for (int k0 = 0; k0 < K; k0 += BK) {
        float4 a0 = *(const float4*)&A[(size_t)(bm + arow) * K + k0 + acol];
        float4 a1 = *(const float4*)&A[(size_t)(bm + arow + 64) * K + k0 + acol];
        float4 b0 = *(const float4*)&B[(size_t)(k0 + brow) * N + bn + bcol];
        __syncthreads();
        As[acol + 0][arow] = a0.x; As[acol + 1][arow] = a0.y;
        As[acol + 2][arow] = a0.z; As[acol + 3][arow] = a0.w;
        As[acol + 0][arow + 64] = a1.x; As[acol + 1][arow + 64] = a1.y;
        As[acol + 2][arow + 64] = a1.z; As[acol + 3][arow + 64] = a1.w;
        *(float4*)&Bs[brow][bcol] = b0;
        __syncthreads();
        #pragma unroll
        for (int kk = 0; kk < BK; ++kk) {
            float4 bv  = *(float4*)&Bs[kk][tx * 4];
            float4 av0 = *(float4*)&As[kk][ty * 8];
            float4 av1 = *(float4*)&As[kk][ty * 8 + 4];
            float ar[8] = {av0.x, av0.y, av0.z, av0.w, av1.x, av1.y, av1.z, av1.w};
            float br[4] = {bv.x, bv.y, bv.z, bv.w};
            #pragma unroll
            for (int i = 0; i < 8; ++i)
                #pragma unroll
                for (int j = 0; j < 4; ++j)
                    acc[i][j] += ar[i] * br[j];
        }
    }

    const int crow = bm + ty * 8;
    const int ccol = bn + tx * 4;
    #pragma unroll
    for (int i = 0; i < 8; ++i) {
        #pragma unroll
        for (int j = 0; j < 4; ++j) {
            float v = acc[i][j] + bias[ccol + j];
            if (res) v += res[(size_t)(crow + i) * N + ccol + j];
            if (act == 1) v = 0.5f * v * (1.0f + erff(v * 0.70710678118654752f));
            C[(size_t)(crow + i) * N + ccol + j] = v;
        }
    }
}

// ---------------- Sliding-window attention ----------------
// 1 wave per (query i, head h). Window j in [i-256, i+256] clipped to [0,S).
__global__ __launch_bounds__(64) void attn_kernel(const float* __restrict__ q,
                                                  const float* __restrict__ k,
                                                  const float* __restrict__ v,
                                                  float* __restrict__ a) {
    const int i = blockIdx.x;
    const int h = blockIdx.y;
    const int l = threadIdx.x;   // 0..63

    __shared__ float qs[64];
    __shared__ float ks[64][65];
    __shared__ float sc[576];

    const size_t hoff = (size_t)h * DHEAD;
    qs[l] = q[(size_t)i * DMODEL + hoff + l];

    const int j0 = max(i - WIN, 0);
    const int j1 = min(i + WIN, S_LEN - 1);
    const int cnt = j1 - j0 + 1;   // <= 513

    for (int cb = 0; cb < cnt; cb += 64) {
        const int nj = min(64, cnt - cb);
        for (int r = 0; r < nj; ++r)
            ks[r][l] = k[(size_t)(j0 + cb + r) * DMODEL + hoff + l];
        __syncthreads();
        if (l < nj) {
            float s = 0.f;
            #pragma unroll
            for (int d = 0; d < 64; ++d) s += qs[d] * ks[l][d];
            sc[cb + l] = s * 0.125f;
        }
        __syncthreads();
    }

    // softmax over sc[0..cnt)
    float m = -3.0e38f;
    for (int t = l; t < cnt; t += 64) m = fmaxf(m, sc[t]);
    #pragma unroll
    for (int off = 32; off; off >>= 1) m = fmaxf(m, __shfl_xor(m, off));
    float z = 0.f;
    for (int t = l; t < cnt; t += 64) {
        float p = expf(sc[t] - m);
        sc[t] = p;
        z += p;
    }
    #pragma unroll
    for (int off = 32; off; off >>= 1) z += __shfl_xor(z, off);
    __syncthreads();

    const float inv = 1.0f / z;
    float accv = 0.f;
    for (int j = 0; j < cnt; ++j)
        accv += sc[j] * v[(size_t)(j0 + j) * DMODEL + hoff + l];
    a[(size_t)i * DMODEL + hoff + l] = accv * inv;
}

// ---------------- Head MLP (single block) ----------------
__global__ __launch_bounds__(256) void head_kernel(const int* __restrict__ ids,
                                                   const float* __restrict__ x,
                                                   const float* __restrict__ w1, const float* __restrict__ b1,
                                                   const float* __restrict__ w2, const float* __restrict__ b2,
                                                   const float* __restrict__ w3, const float* __restrict__ b3,
                                                   float* __restrict__ out) {
    const int tid = threadIdx.x;
    __shared__ int sred[256];
    int loc = -1;
    for (int i = tid; i < S_LEN; i += 256)
        if (ids[i] == 2) loc = i;   // strided: later i overwrites, but need global max
    // loc is max within this thread's stride already (i increasing)
    sred[tid] = loc;
    __syncthreads();
    for (int s2 = 128; s2; s2 >>= 1) {
        if (tid < s2) sred[tid] = max(sred[tid], sred[tid + s2]);
        __syncthreads();
    }
    const int sep = sred[0] < 0 ? (S_LEN - 1) : sred[0];

    __shared__ float emb[DMODEL];
    __shared__ float z1[512];
    __shared__ float z2[256];
    __shared__ float fred[256];

    for (int d = tid; d < DMODEL; d += 256) emb[d] = x[(size_t)sep * DMODEL + d];
    __syncthreads();

    for (int o = tid; o < 512; o += 256) {
        float s = b1[o];
        for (int d = 0; d < DMODEL; ++d) s += emb[d] * w1[(size_t)d * 512 + o];
        z1[o] = fmaxf(s, 0.f);
    }
    __syncthreads();

    {
        float s = b2[tid];
        for (int d = 0; d < 512; ++d) s += z1[d] * w2[(size_t)d * 256 + tid];
        z2[tid] = fmaxf(s, 0.f);
    }
    __syncthreads();

    fred[tid] = z2[tid] * w3[tid];
    __syncthreads();
    for (int s2 = 128; s2; s2 >>= 1) {
        if (tid < s2) fred[tid] += fred[tid + s2];
        __syncthreads();
    }
    if (tid == 0) out[0] = tanhf(fred[0] + b3[0]);
}

// ---------------- launch ----------------

extern "C" void kernel_launch(void* const* d_in, const int* in_sizes, int n_in,
                              void* d_out, int out_size, void* d_ws, size_t ws_size,
                              hipStream_t stream) {
    const int*   ids      = (const int*)d_in[0];
    const float* word_emb = (const float*)d_in[2];
    const float* pos_emb  = (const float*)d_in[3];
    const float* emb_s    = (const float*)d_in[4];
    const float* emb_b    = (const float*)d_in[5];
    const float* Wq = (const float*)d_in[6];
    const float* bq = (const float*)d_in[7];
    const float* Wk = (const float*)d_in[8];
    const float* bk = (const float*)d_in[9];
    const float* Wv = (const float*)d_in[10];
    const float* bv = (const float*)d_in[11];
    const float* Wo = (const float*)d_in[12];
    const float* bo = (const float*)d_in[13];
    const float* l1s = (const float*)d_in[14];
    const float* l1b = (const float*)d_in[15];
    const float* W1 = (const float*)d_in[16];
    const float* b1 = (const float*)d_in[17];
    const float* W2 = (const float*)d_in[18];
    const float* b2 = (const float*)d_in[19];
    const float* l2s = (const float*)d_in[20];
    const float* l2b = (const float*)d_in[21];
    const float* h1w = (const float*)d_in[22];
    const float* h1b = (const float*)d_in[23];
    const float* h2w = (const float*)d_in[24];
    const float* h2b = (const float*)d_in[25];
    const float* h3w = (const float*)d_in[26];
    const float* h3b = (const float*)d_in[27];

    const size_t SD = (size_t)S_LEN * DMODEL;
    float* ws = (float*)d_ws;
    float* x  = ws;
    float* q  = x + SD;
    float* k  = q + SD;
    float* v  = k + SD;
    float* a  = v + SD;
    float* t  = a + SD;
    float* hb = t + SD;                 // S x FF
    // total = 6*SD + S*FF floats = ~126 MB

    embed_ln_kernel<<<S_LEN, 256, 0, stream>>>(ids, word_emb, pos_emb, emb_s, emb_b, x);

    const dim3 g768(S_LEN / BM, DMODEL / BN);   // 32 x 12
    const dim3 gff (S_LEN / BM, FFDIM / BN);    // 32 x 48

    for (int l = 0; l < NLAYER; ++l) {
        const size_t dd = (size_t)DMODEL * DMODEL;
        const float* wq = Wq + (size_t)l * dd;
        const float* wk = Wk + (size_t)l * dd;
        const float* wv = Wv + (size_t)l * dd;
        const float* wo = Wo + (size_t)l * dd;
        const float* bql = bq + (size_t)l * DMODEL;
        const float* bkl = bk + (size_t)l * DMODEL;
        const float* bvl = bv + (size_t)l * DMODEL;
        const float* bol = bo + (size_t)l * DMODEL;
        const float* w1l = W1 + (size_t)l * DMODEL * FFDIM;
        const float* b1l = b1 + (size_t)l * FFDIM;
        const float* w2l = W2 + (size_t)l * FFDIM * DMODEL;
        const float* b2l = b2 + (size_t)l * DMODEL;

        gemm_kernel<<<g768, 256, 0, stream>>>(x, wq, bql, nullptr, q, S_LEN, DMODEL, DMODEL, 0);
        gemm_kernel<<<g768, 256, 0, stream>>>(x, wk, bkl, nullptr, k, S_LEN, DMODEL, DMODEL, 0);
        gemm_kernel<<<g768, 256, 0, stream>>>(x, wv, bvl, nullptr, v, S_LEN, DMODEL, DMODEL, 0);

        attn_kernel<<<dim3(S_LEN, NHEAD), 64, 0, stream>>>(q, k, v, a);

        gemm_kernel<<<g768, 256, 0, stream>>>(a, wo, bol, x, t, S_LEN, DMODEL, DMODEL, 0);
        ln_kernel<<<S_LEN, 256, 0, stream>>>(t, l1s + (size_t)l * DMODEL, l1b + (size_t)l * DMODEL, x);

        gemm_kernel<<<gff, 256, 0, stream>>>(x, w1l, b1l, nullptr, hb, S_LEN, FFDIM, DMODEL, 1);
        gemm_kernel<<<g768, 256, 0, stream>>>(hb, w2l, b2l, x, t, S_LEN, DMODEL, FFDIM, 0);
        ln_kernel<<<S_LEN, 256, 0, stream>>>(t, l2s + (size_t)l * DMODEL, l2b + (size_t)l * DMODEL, x);
    }

    head_kernel<<<1, 256, 0, stream>>>(ids, x, h1w, h1b, h2w, h2b, h3w, h3b, (float*)d_out);
}

// Round 2
// 3276.225 us; speedup vs baseline: 8.3505x; 8.3505x over previous
//
#include <hip/hip_runtime.h>
#include <math.h>

#define S_LEN 4096
#define DMODEL 768
#define NHEAD 12
#define DHEAD 64
#define FFDIM 3072
#define NLAYER 12
#define WIN 256
#define QKVN 2304

typedef __bf16 bf16x8 __attribute__((ext_vector_type(8)));
typedef unsigned short u16x8 __attribute__((ext_vector_type(8)));
typedef float f32x4 __attribute__((ext_vector_type(4)));

__device__ inline unsigned short f2bf(float f) {
    unsigned int u = __float_as_uint(f);
    u += 0x7fff + ((u >> 16) & 1);
    return (unsigned short)(u >> 16);
}

__device__ inline void gload16(const void* g, void* l) {
    __builtin_amdgcn_global_load_lds((const __attribute__((address_space(1))) void*)g,
                                     (__attribute__((address_space(3))) void*)l, 16, 0, 0);
}

// ---------------- LayerNorm ----------------

__device__ inline void block_reduce2(float& sum, float& sq) {
    #pragma unroll
    for (int off = 32; off; off >>= 1) {
        sum += __shfl_xor(sum, off);
        sq  += __shfl_xor(sq, off);
    }
    __shared__ float red[8];
    int wid = threadIdx.x >> 6, lane = threadIdx.x & 63;
    if (lane == 0) { red[wid] = sum; red[wid + 4] = sq; }
    __syncthreads();
    sum = red[0] + red[1] + red[2] + red[3];
    sq  = red[4] + red[5] + red[6] + red[7];
    __syncthreads();
}

// out fp32 + bf16 copy
__global__ __launch_bounds__(256) void ln_kernel(const float* __restrict__ in,
                                                 const float* __restrict__ s,
                                                 const float* __restrict__ b,
                                                 float* __restrict__ out,
                                                 unsigned short* __restrict__ outb) {
    int row = blockIdx.x, tid = threadIdx.x;
    const float* p = in + (size_t)row * DMODEL;
    float v0 = p[tid], v1 = p[tid + 256], v2 = p[tid + 512];
    float sum = v0 + v1 + v2;
    float sq  = v0 * v0 + v1 * v1 + v2 * v2;
    block_reduce2(sum, sq);
    float mu = sum * (1.0f / DMODEL);
    float var = sq * (1.0f / DMODEL) - mu * mu;
    float rs = rsqrtf(var + 1e-5f);
    float* o = out + (size_t)row * DMODEL;
    unsigned short* ob = outb + (size_t)row * DMODEL;
    float r0 = (v0 - mu) * rs * s[tid]       + b[tid];
    float r1 = (v1 - mu) * rs * s[tid + 256] + b[tid + 256];
    float r2 = (v2 - mu) * rs * s[tid + 512] + b[tid + 512];
    o[tid] = r0; o[tid + 256] = r1; o[tid + 512] = r2;
    ob[tid] = f2bf(r0); ob[tid + 256] = f2bf(r1); ob[tid + 512] = f2bf(r2);
}

__global__ __launch_bounds__(256) void embed_ln_kernel(const int* __restrict__ ids,
                                                       const float* __restrict__ wemb,
                                                       const float* __restrict__ pemb,
                                                       const float* __restrict__ s,
                                                       const float* __restrict__ b,
                                                       float* __restrict__ out,
                                                       unsigned short* __restrict__ outb) {
    int row = blockIdx.x, tid = threadIdx.x;
    int id = ids[row];
    const float* wp = wemb + (size_t)id * DMODEL;
    const float* pp = pemb + (size_t)(row + 2) * DMODEL;
    float v0 = wp[tid] + pp[tid];
    float v1 = wp[tid + 256] + pp[tid + 256];
    float v2 = wp[tid + 512] + pp[tid + 512];
    float sum = v0 + v1 + v2;
    float sq  = v0 * v0 + v1 * v1 + v2 * v2;
    block_reduce2(sum, sq);
    float mu = sum * (1.0f / DMODEL);
    float var = sq * (1.0f / DMODEL) - mu * mu;
    float rs = rsqrtf(var + 1e-5f);
    float* o = out + (size_t)row * DMODEL;
    unsigned short* ob = outb + (size_t)row * DMODEL;
    float r0 = (v0 - mu) * rs * s[tid]       + b[tid];
    float r1 = (v1 - mu) * rs * s[tid + 256] + b[tid + 256];
    float r2 = (v2 - mu) * rs * s[tid + 512] + b[tid + 512];
    o[tid] = r0; o[tid + 256] = r1; o[tid + 512] = r2;
    ob[tid] = f2bf(r0); ob[tid + 256] = f2bf(r1); ob[tid + 512] = f2bf(r2);
}

// ---------------- weight transpose + fp32->bf16 ----------------
// dst[c][r] = bf16(src[r][c]); grid (C/32, R/32), block 256
__global__ __launch_bounds__(256) void transpose_cvt(const float* __restrict__ src,
                                                     unsigned short* __restrict__ dst,
                                                     int R, int C) {
    __shared__ float tile[32][33];
    const int bx = blockIdx.x * 32;   // C dir
    const int by = blockIdx.y * 32;   // R dir
    const int tx = threadIdx.x & 31, ty = threadIdx.x >> 5;
    #pragma unroll
    for (int k = 0; k < 4; ++k)
        tile[ty + k * 8][tx] = src[(size_t)(by + ty + k * 8) * C + bx + tx];
    __syncthreads();
    #pragma unroll
    for (int k = 0; k < 4; ++k)
        dst[(size_t)(bx + ty + k * 8) * R + by + tx] = f2bf(tile[tx][ty + k * 8]);
}

__global__ __launch_bounds__(256) void bias_concat(const float* __restrict__ bq,
                                                   const float* __restrict__ bk,
                                                   const float* __restrict__ bv,
                                                   float* __restrict__ out) {
    int l = blockIdx.x, t = threadIdx.x;
    for (int i = t; i < DMODEL; i += 256) {
        out[(size_t)l * QKVN + i]              = bq[(size_t)l * DMODEL + i];
        out[(size_t)l * QKVN + DMODEL + i]     = bk[(size_t)l * DMODEL + i];
        out[(size_t)l * QKVN + 2 * DMODEL + i] = bv[(size_t)l * DMODEL + i];
    }
}

// ---------------- bf16 MFMA GEMM ----------------
// C[M][N] = A[M][K] @ Bt[N][K]^T + bias (+res)(+gelu)
// MODE 0: fp32 out = acc+bias+res; 1: bf16 out = acc+bias; 2: bf16 out = gelu(acc+bias)
template<int MODE>
__global__ __launch_bounds__(256) void mfma_gemm(const unsigned short* __restrict__ A,
                                                 const unsigned short* __restrict__ Bt,
                                                 const float* __restrict__ bias,
                                                 const float* __restrict__ res,
                                                 void* __restrict__ Cout,
                                                 int M, int N, int K) {
    __shared__ unsigned short As[128 * 64];
    __shared__ unsigned short Bs[128 * 64];
    const int tid = threadIdx.x;
    const int wv = tid >> 6, lane = tid & 63;
    const int bm = blockIdx.x * 128, bn = blockIdx.y * 128;
    const int wr = (wv >> 1) * 64, wc = (wv & 1) * 64;
    const int l15 = lane & 15, g = lane >> 4;

    f32x4 acc[4][4];
    #pragma unroll
    for (int m = 0; m < 4; ++m)
        #pragma unroll
        for (int n = 0; n < 4; ++n)
            #pragma unroll
            for (int e = 0; e < 4; ++e) acc[m][n][e] = 0.f;

    const int srow = tid >> 3;        // 0..31
    const int scol = (tid & 7) * 8;   // ushort offset

    for (int k0 = 0; k0 < K; k0 += 64) {
        __syncthreads();
        #pragma unroll
        for (int c = 0; c < 4; ++c) {
            gload16(A  + (size_t)(bm + c * 32 + srow) * K + k0 + scol,
                    (char*)As + c * 4096 + wv * 1024);
            gload16(Bt + (size_t)(bn + c * 32 + srow) * K + k0 + scol,
                    (char*)Bs + c * 4096 + wv * 1024);
        }
        __syncthreads();
        #pragma unroll
        for (int kk = 0; kk < 2; ++kk) {
            bf16x8 af[4], bfr[4];
            #pragma unroll
            for (int m = 0; m < 4; ++m)
                af[m] = *(const bf16x8*)(As + (wr + m * 16 + l15) * 64 + kk * 32 + g * 8);
            #pragma unroll
            for (int n = 0; n < 4; ++n)
                bfr[n] = *(const bf16x8*)(Bs + (wc + n * 16 + l15) * 64 + kk * 32 + g * 8);
            #pragma unroll
            for (int m = 0; m < 4; ++m)
                #pragma unroll
                for (int n = 0; n < 4; ++n)
                    acc[m][n] = __builtin_amdgcn_mfma_f32_16x16x32_bf16(af[m], bfr[n], acc[m][n], 0, 0, 0);
        }
    }

    #pragma unroll
    for (int m = 0; m < 4; ++m) {
        const int row0 = bm + wr + m * 16 + g * 4;
        #pragma unroll
        for (int n = 0; n < 4; ++n) {
            const int col = bn + wc + n * 16 + l15;
            const float bb = bias[col];
            #pragma unroll
            for (int r = 0; r < 4; ++r) {
                float v = acc[m][n][r] + bb;
                if (MODE == 0) {
                    v += res[(size_t)(row0 + r) * N + col];
                    ((float*)Cout)[(size_t)(row0 + r) * N + col] = v;
                } else if (MODE == 1) {
                    ((unsigned short*)Cout)[(size_t)(row0 + r) * N + col] = f2bf(v);
                } else {
                    float gv = 0.5f * v * (1.0f + erff(v * 0.70710678118654752f));
                    ((unsigned short*)Cout)[(size_t)(row0 + r) * N + col] = f2bf(gv);
                }
            }
        }
    }
}

// ---------------- MFMA flash attention (sliding window) ----------------
// grid (S/64, H), block 256 = 4 waves, each wave owns 16 query rows.
__global__ __launch_bounds__(256) void attn_mfma(const unsigned short* __restrict__ qkv,
                                                 const int* __restrict__ msk,
                                                 unsigned short* __restrict__ aout) {
    __shared__ unsigned short Ks[64 * 64];
    __shared__ unsigned short Vt[64 * 64];
    __shared__ unsigned short Ps[4][16 * 64];
    const int tid = threadIdx.x;
    const int wv = tid >> 6, lane = tid & 63;
    const int l15 = lane & 15, g = lane >> 4;
    const int h = blockIdx.y;
    const int q0 = blockIdx.x * 64;

    // Q fragments (this wave's 16 rows), kept in registers
    const int qrow = q0 + wv * 16 + l15;
    bf16x8 qf[2];
    #pragma unroll
    for (int kk = 0; kk < 2; ++kk)
        qf[kk] = *(const bf16x8*)(qkv + (size_t)qrow * QKVN + h * 64 + kk * 32 + g * 8);

    f32x4 o[4];
    #pragma unroll
    for (int n = 0; n < 4; ++n)
        #pragma unroll
        for (int e = 0; e < 4; ++e) o[n][e] = 0.f;
    float mst[4] = {-3e38f, -3e38f, -3e38f, -3e38f};
    float lst[4] = {0.f, 0.f, 0.f, 0.f};

    const int srow = tid >> 3;        // 0..31
    const int scol = (tid & 7) * 8;   // ushort offset (d)

    for (int c = 0; c < 9; ++c) {
        const int kc = q0 - 256 + c * 64;
        __syncthreads();
        // stage K [key][d] via global_load_lds (rows clamped; masked later)
        #pragma unroll
        for (int cc = 0; cc < 2; ++cc) {
            int krow = kc + cc * 32 + srow;
            krow = min(max(krow, 0), S_LEN - 1);
            gload16(qkv + (size_t)krow * QKVN + DMODEL + h * 64 + scol,
                    (char*)Ks + cc * 4096 + wv * 1024);
        }
        // stage V transposed: Vt[d][key]
        #pragma unroll
        for (int cc = 0; cc < 2; ++cc) {
            int key = cc * 32 + srow;
            int vrow = min(max(kc + key, 0), S_LEN - 1);
            u16x8 vvv = *(const u16x8*)(qkv + (size_t)vrow * QKVN + 2 * DMODEL + h * 64 + scol);
            #pragma unroll
            for (int j = 0; j < 8; ++j)
                Vt[(scol + j) * 64 + key] = vvv[j];
        }
        __syncthreads();

        // S = Q K^T  (C-frag: col=key n*16+l15, row=q 4g+r)
        f32x4 s[4];
        #pragma unroll
        for (int n = 0; n < 4; ++n)
            #pragma unroll
            for (int e = 0; e < 4; ++e) s[n][e] = 0.f;
        #pragma unroll
        for (int kk = 0; kk < 2; ++kk) {
            #pragma unroll
            for (int n = 0; n < 4; ++n) {
                bf16x8 kf = *(const bf16x8*)(Ks + (n * 16 + l15) * 64 + kk * 32 + g * 8);
                s[n] = __builtin_amdgcn_mfma_f32_16x16x32_bf16(qf[kk], kf, s[n], 0, 0, 0);
            }
        }

        // mask + online softmax
        float pv[4][4];
        const int qbase = q0 + wv * 16 + g * 4;
        #pragma unroll
        for (int n = 0; n < 4; ++n) {
            const int key = kc + n * 16 + l15;
            const bool kin = (key >= 0) && (key < S_LEN);
            const int mv = kin ? msk[key] : 0;
            #pragma unroll
            for (int r = 0; r < 4; ++r) {
                const int qa = qbase + r;
                const bool valid = (mv != 0) && (abs(key - qa) <= WIN);
                pv[n][r] = valid ? s[n][r] * 0.125f : -1e9f;
            }
        }
        float scold[4];
        #pragma unroll
        for (int r = 0; r < 4; ++r) {
            float mx = fmaxf(fmaxf(pv[0][r], pv[1][r]), fmaxf(pv[2][r], pv[3][r]));
            mx = fmaxf(mx, __shfl_xor(mx, 1));
            mx = fmaxf(mx, __shfl_xor(mx, 2));
            mx = fmaxf(mx, __shfl_xor(mx, 4));
            mx = fmaxf(mx, __shfl_xor(mx, 8));
            const float nm = fmaxf(mst[r], mx);
            scold[r] = expf(mst[r] - nm);
            float sum = 0.f;
            #pragma unroll
            for (int n = 0; n < 4; ++n) { pv[n][r] = expf(pv[n][r] - nm); sum += pv[n][r]; }
            sum += __shfl_xor(sum, 1); sum += __shfl_xor(sum, 2);
            sum += __shfl_xor(sum, 4); sum += __shfl_xor(sum, 8);
            lst[r] = lst[r] * scold[r] + sum;
            mst[r] = nm;
        }
        #pragma unroll
        for (int n = 0; n < 4; ++n)
            #pragma unroll
            for (int r = 0; r < 4; ++r)
                o[n][r] *= scold[r];

        // write P (bf16) to this wave's LDS region: [q_local 16][key 64]
        #pragma unroll
        for (int n = 0; n < 4; ++n)
            #pragma unroll
            for (int r = 0; r < 4; ++r)
                Ps[wv][(g * 4 + r) * 64 + n * 16 + l15] = f2bf(pv[n][r]);

        // O += P @ V  (A = P[q][key], B = V[key][d] read from Vt[d][key])
        #pragma unroll
        for (int kk = 0; kk < 2; ++kk) {
            bf16x8 pf = *(const bf16x8*)(Ps[wv] + l15 * 64 + kk * 32 + g * 8);
            #pragma unroll
            for (int nd = 0; nd < 4; ++nd) {
                bf16x8 vf = *(const bf16x8*)(Vt + (nd * 16 + l15) * 64 + kk * 32 + g * 8);
                o[nd] = __builtin_amdgcn_mfma_f32_16x16x32_bf16(pf, vf, o[nd], 0, 0, 0);
            }
        }
    }

    #pragma unroll
    for (int r = 0; r < 4; ++r) {
        const float inv = 1.0f / lst[r];
        const int qa = q0 + wv * 16 + g * 4 + r;
        #pragma unroll
        for (int nd = 0; nd < 4; ++nd)
            aout[(size_t)qa * DMODEL + h * 64 + nd * 16 + l15] = f2bf(o[nd][r] * inv);
    }
}

// ---------------- Head MLP ----------------
__global__ __launch_bounds__(256) void head_kernel(const int* __restrict__ ids,
                                                   const float* __restrict__ x,
                                                   const float* __restrict__ w1, const float* __restrict__ b1,
                                                   const float* __restrict__ w2, const float* __restrict__ b2,
                                                   const float* __restrict__ w3, const float* __restrict__ b3,
                                                   float* __restrict__ out) {
    const int tid = threadIdx.x;
    __shared__ int sred[256];
    int loc = -1;
    for (int i = tid; i < S_LEN; i += 256)
        if (ids[i] == 2) loc = i;
    sred[tid] = loc;
    __syncthreads();
    for (int s2 = 128; s2; s2 >>= 1) {
        if (tid < s2) sred[tid] = max(sred[tid], sred[tid + s2]);
        __syncthreads();
    }
    const int sep = sred[0] < 0 ? (S_LEN - 1) : sred[0];

    __shared__ float emb[DMODEL];
    __shared__ float z1[512];
    __shared__ float z2[256];
    __shared__ float fred[256];

    for (int d = tid; d < DMODEL; d += 256) emb[d] = x[(size_t)sep * DMODEL + d];
    __syncthreads();

    for (int o = tid; o < 512; o += 256) {
        float s = b1[o];
        for (int d = 0; d < DMODEL; ++d) s += emb[d] * w1[(size_t)d * 512 + o];
        z1[o] = fmaxf(s, 0.f);
    }
    __syncthreads();
    {
        float s = b2[tid];
        for (int d = 0; d < 512; ++d) s += z1[d] * w2[(size_t)d * 256 + tid];
        z2[tid] = fmaxf(s, 0.f);
    }
    __syncthreads();
    fred[tid] = z2[tid] * w3[tid];
    __syncthreads();
    for (int s2 = 128; s2; s2 >>= 1) {
        if (tid < s2) fred[tid] += fred[tid + s2];
        __syncthreads();
    }
    if (tid == 0) out[0] = tanhf(fred[0] + b3[0]);
}

// ---------------- launch ----------------

extern "C" void kernel_launch(void* const* d_in, const int* in_sizes, int n_in,
                              void* d_out, int out_size, void* d_ws, size_t ws_size,
                              hipStream_t stream) {
    const int*   ids      = (const int*)d_in[0];
    const int*   amask    = (const int*)d_in[1];
    const float* word_emb = (const float*)d_in[2];
    const float* pos_emb  = (const float*)d_in[3];
    const float* emb_s    = (const float*)d_in[4];
    const float* emb_b    = (const float*)d_in[5];
    const float* Wq = (const float*)d_in[6];
    const float* bq = (const float*)d_in[7];
    const float* Wk = (const float*)d_in[8];
    const float* bk = (const float*)d_in[9];
    const float* Wv = (const float*)d_in[10];
    const float* bv = (const float*)d_in[11];
    const float* Wo = (const float*)d_in[12];
    const float* bo = (const float*)d_in[13];
    const float* l1s = (const float*)d_in[14];
    const float* l1b = (const float*)d_in[15];
    const float* W1 = (const float*)d_in[16];
    const float* b1 = (const float*)d_in[17];
    const float* W2 = (const float*)d_in[18];
    const float* b2 = (const float*)d_in[19];
    const float* l2s = (const float*)d_in[20];
    const float* l2b = (const float*)d_in[21];
    const float* h1w = (const float*)d_in[22];
    const float* h1b = (const float*)d_in[23];
    const float* h2w = (const float*)d_in[24];
    const float* h2b = (const float*)d_in[25];
    const float* h3w = (const float*)d_in[26];
    const float* h3b = (const float*)d_in[27];

    char* ws = (char*)d_ws;
    float* x          = (float*)(ws);                              // 12.58 MB
    float* t          = (float*)(ws + 12582912);                   // 12.58 MB
    unsigned short* xb   = (unsigned short*)(ws + 25165824);       // 6.29 MB
    unsigned short* qkv  = (unsigned short*)(ws + 31457280);       // 18.87 MB
    unsigned short* a    = (unsigned short*)(ws + 50331648);       // 6.29 MB
    unsigned short* hb   = (unsigned short*)(ws + 56623104);       // 25.17 MB
    unsigned short* WqkvT= (unsigned short*)(ws + 81788928);       // 3.54 MB
    unsigned short* WoT  = (unsigned short*)(ws + 85327872);       // 1.18 MB
    unsigned short* W1T  = (unsigned short*)(ws + 86507520);       // 4.72 MB
    unsigned short* W2T  = (unsigned short*)(ws + 91226112);       // 4.72 MB
    float* biascat       = (float*)(ws + 95944704);                // 0.11 MB

    bias_concat<<<NLAYER, 256, 0, stream>>>(bq, bk, bv, biascat);
    embed_ln_kernel<<<S_LEN, 256, 0, stream>>>(ids, word_emb, pos_emb, emb_s, emb_b, x, xb);

    const size_t dd = (size_t)DMODEL * DMODEL;
    const size_t df = (size_t)DMODEL * FFDIM;

    for (int l = 0; l < NLAYER; ++l) {
        // weight transposes (fp32 -> bf16, [K][N] -> [N][K])
        transpose_cvt<<<dim3(24, 24), 256, 0, stream>>>(Wq + l * dd, WqkvT,               DMODEL, DMODEL);
        transpose_cvt<<<dim3(24, 24), 256, 0, stream>>>(Wk + l * dd, WqkvT + dd,          DMODEL, DMODEL);
        transpose_cvt<<<dim3(24, 24), 256, 0, stream>>>(Wv + l * dd, WqkvT + 2 * dd,      DMODEL, DMODEL);
        transpose_cvt<<<dim3(24, 24), 256, 0, stream>>>(Wo + l * dd, WoT,                 DMODEL, DMODEL);
        transpose_cvt<<<dim3(96, 24), 256, 0, stream>>>(W1 + l * df, W1T,                 DMODEL, FFDIM);
        transpose_cvt<<<dim3(24, 96), 256, 0, stream>>>(W2 + l * df, W2T,                 FFDIM, DMODEL);

        // QKV fused
        mfma_gemm<1><<<dim3(32, 18), 256, 0, stream>>>(xb, WqkvT, biascat + (size_t)l * QKVN,
                                                       nullptr, qkv, S_LEN, QKVN, DMODEL);
        attn_mfma<<<dim3(S_LEN / 64, NHEAD), 256, 0, stream>>>(qkv, amask, a);

        mfma_gemm<0><<<dim3(32, 6), 256, 0, stream>>>(a, WoT, bo + (size_t)l * DMODEL,
                                                      x, t, S_LEN, DMODEL, DMODEL);
        ln_kernel<<<S_LEN, 256, 0, stream>>>(t, l1s + (size_t)l * DMODEL, l1b + (size_t)l * DMODEL, x, xb);

        mfma_gemm<2><<<dim3(32, 24), 256, 0, stream>>>(xb, W1T, b1 + (size_t)l * FFDIM,
                                                       nullptr, hb, S_LEN, FFDIM, DMODEL);
        mfma_gemm<0><<<dim3(32, 6), 256, 0, stream>>>(hb, W2T, b2 + (size_t)l * DMODEL,
                                                      x, t, S_LEN, DMODEL, FFDIM);
        ln_kernel<<<S_LEN, 256, 0, stream>>>(t, l2s + (size_t)l * DMODEL, l2b + (size_t)l * DMODEL, x, xb);
    }

    head_kernel<<<1, 256, 0, stream>>>(ids, x, h1w, h1b, h2w, h2b, h3w, h3b, (float*)d_out);
}

// Round 3
// 3107.614 us; speedup vs baseline: 8.8036x; 1.0543x over previous
//
#include <hip/hip_runtime.h>
#include <math.h>

#define S_LEN 4096
#define DMODEL 768
#define NHEAD 12
#define DHEAD 64
#define FFDIM 3072
#define NLAYER 12
#define WIN 256
#define QKVN 2304

typedef __bf16 bf16x8 __attribute__((ext_vector_type(8)));
typedef unsigned short u16x8 __attribute__((ext_vector_type(8)));
typedef float f32x4 __attribute__((ext_vector_type(4)));

__device__ inline unsigned short f2bf(float f) {
    unsigned int u = __float_as_uint(f);
    u += 0x7fff + ((u >> 16) & 1);
    return (unsigned short)(u >> 16);
}

__device__ inline void gload16(const void* g, void* l) {
    __builtin_amdgcn_global_load_lds((const __attribute__((address_space(1))) void*)g,
                                     (__attribute__((address_space(3))) void*)l, 16, 0, 0);
}

// ---------------- LayerNorm ----------------

__device__ inline void block_reduce2(float& sum, float& sq) {
    #pragma unroll
    for (int off = 32; off; off >>= 1) {
        sum += __shfl_xor(sum, off);
        sq  += __shfl_xor(sq, off);
    }
    __shared__ float red[8];
    int wid = threadIdx.x >> 6, lane = threadIdx.x & 63;
    if (lane == 0) { red[wid] = sum; red[wid + 4] = sq; }
    __syncthreads();
    sum = red[0] + red[1] + red[2] + red[3];
    sq  = red[4] + red[5] + red[6] + red[7];
    __syncthreads();
}

// out fp32 + bf16 copy
__global__ __launch_bounds__(256) void ln_kernel(const float* __restrict__ in,
                                                 const float* __restrict__ s,
                                                 const float* __restrict__ b,
                                                 float* __restrict__ out,
                                                 unsigned short* __restrict__ outb) {
    int row = blockIdx.x, tid = threadIdx.x;
    const float* p = in + (size_t)row * DMODEL;
    float v0 = p[tid], v1 = p[tid + 256], v2 = p[tid + 512];
    float sum = v0 + v1 + v2;
    float sq  = v0 * v0 + v1 * v1 + v2 * v2;
    block_reduce2(sum, sq);
    float mu = sum * (1.0f / DMODEL);
    float var = sq * (1.0f / DMODEL) - mu * mu;
    float rs = rsqrtf(var + 1e-5f);
    float* o = out + (size_t)row * DMODEL;
    unsigned short* ob = outb + (size_t)row * DMODEL;
    float r0 = (v0 - mu) * rs * s[tid]       + b[tid];
    float r1 = (v1 - mu) * rs * s[tid + 256] + b[tid + 256];
    float r2 = (v2 - mu) * rs * s[tid + 512] + b[tid + 512];
    o[tid] = r0; o[tid + 256] = r1; o[tid + 512] = r2;
    ob[tid] = f2bf(r0); ob[tid + 256] = f2bf(r1); ob[tid + 512] = f2bf(r2);
}

__global__ __launch_bounds__(256) void embed_ln_kernel(const int* __restrict__ ids,
                                                       const float* __restrict__ wemb,
                                                       const float* __restrict__ pemb,
                                                       const float* __restrict__ s,
                                                       const float* __restrict__ b,
                                                       float* __restrict__ out,
                                                       unsigned short* __restrict__ outb) {
    int row = blockIdx.x, tid = threadIdx.x;
    int id = ids[row];
    const float* wp = wemb + (size_t)id * DMODEL;
    const float* pp = pemb + (size_t)(row + 2) * DMODEL;
    float v0 = wp[tid] + pp[tid];
    float v1 = wp[tid + 256] + pp[tid + 256];
    float v2 = wp[tid + 512] + pp[tid + 512];
    float sum = v0 + v1 + v2;
    float sq  = v0 * v0 + v1 * v1 + v2 * v2;
    block_reduce2(sum, sq);
    float mu = sum * (1.0f / DMODEL);
    float var = sq * (1.0f / DMODEL) - mu * mu;
    float rs = rsqrtf(var + 1e-5f);
    float* o = out + (size_t)row * DMODEL;
    unsigned short* ob = outb + (size_t)row * DMODEL;
    float r0 = (v0 - mu) * rs * s[tid]       + b[tid];
    float r1 = (v1 - mu) * rs * s[tid + 256] + b[tid + 256];
    float r2 = (v2 - mu) * rs * s[tid + 512] + b[tid + 512];
    o[tid] = r0; o[tid + 256] = r1; o[tid + 512] = r2;
    ob[tid] = f2bf(r0); ob[tid + 256] = f2bf(r1); ob[tid + 512] = f2bf(r2);
}

// ---------------- merged per-layer weight transpose + cvt ----------------
// One dispatch converts all 6 weight matrices of a layer.
// Tiles: 4 x (768x768) = 4*576, W1 (768x3072) = 2304, W2 (3072x768) = 2304. Total 6912.
__global__ __launch_bounds__(256) void transpose_all(const float* __restrict__ wq,
                                                     const float* __restrict__ wk,
                                                     const float* __restrict__ wv,
                                                     const float* __restrict__ wo,
                                                     const float* __restrict__ w1,
                                                     const float* __restrict__ w2,
                                                     unsigned short* __restrict__ dq,
                                                     unsigned short* __restrict__ dk,
                                                     unsigned short* __restrict__ dv,
                                                     unsigned short* __restrict__ dwo,
                                                     unsigned short* __restrict__ d1,
                                                     unsigned short* __restrict__ d2) {
    const int id = blockIdx.x;
    const float* src; unsigned short* dst; int C, R, bx, by;
    if (id < 2304) {
        const int m = id / 576, t2 = id % 576;
        src = (m == 0) ? wq : (m == 1) ? wk : (m == 2) ? wv : wo;
        dst = (m == 0) ? dq : (m == 1) ? dk : (m == 2) ? dv : dwo;
        R = 768; C = 768; bx = (t2 % 24) * 32; by = (t2 / 24) * 32;
    } else if (id < 4608) {
        const int t2 = id - 2304;
        src = w1; dst = d1; R = 768; C = 3072;
        bx = (t2 % 96) * 32; by = (t2 / 96) * 32;
    } else {
        const int t2 = id - 4608;
        src = w2; dst = d2; R = 3072; C = 768;
        bx = (t2 % 24) * 32; by = (t2 / 24) * 32;
    }
    __shared__ float tile[32][33];
    const int tx = threadIdx.x & 31, ty = threadIdx.x >> 5;
    #pragma unroll
    for (int k = 0; k < 4; ++k)
        tile[ty + k * 8][tx] = src[(size_t)(by + ty + k * 8) * C + bx + tx];
    __syncthreads();
    #pragma unroll
    for (int k = 0; k < 4; ++k)
        dst[(size_t)(bx + ty + k * 8) * R + by + tx] = f2bf(tile[tx][ty + k * 8]);
}

__global__ __launch_bounds__(256) void bias_concat(const float* __restrict__ bq,
                                                   const float* __restrict__ bk,
                                                   const float* __restrict__ bv,
                                                   float* __restrict__ out) {
    int l = blockIdx.x, t = threadIdx.x;
    for (int i = t; i < DMODEL; i += 256) {
        out[(size_t)l * QKVN + i]              = bq[(size_t)l * DMODEL + i];
        out[(size_t)l * QKVN + DMODEL + i]     = bk[(size_t)l * DMODEL + i];
        out[(size_t)l * QKVN + 2 * DMODEL + i] = bv[(size_t)l * DMODEL + i];
    }
}

// ---------------- bf16 MFMA GEMM ----------------
// C[M][N] = A[M][K] @ Bt[N][K]^T + bias (+res)(+gelu)
// MODE 0: fp32 out = acc+bias+res; 1: bf16 out = acc+bias; 2: bf16 out = gelu(acc+bias)
template<int MODE>
__global__ __launch_bounds__(256) void mfma_gemm(const unsigned short* __restrict__ A,
                                                 const unsigned short* __restrict__ Bt,
                                                 const float* __restrict__ bias,
                                                 const float* __restrict__ res,
                                                 void* __restrict__ Cout,
                                                 int M, int N, int K) {
    __shared__ unsigned short As[128 * 64];
    __shared__ unsigned short Bs[128 * 64];
    const int tid = threadIdx.x;
    const int wv = tid >> 6, lane = tid & 63;
    const int bm = blockIdx.x * 128, bn = blockIdx.y * 128;
    const int wr = (wv >> 1) * 64, wc = (wv & 1) * 64;
    const int l15 = lane & 15, g = lane >> 4;

    f32x4 acc[4][4];
    #pragma unroll
    for (int m = 0; m < 4; ++m)
        #pragma unroll
        for (int n = 0; n < 4; ++n)
            #pragma unroll
            for (int e = 0; e < 4; ++e) acc[m][n][e] = 0.f;

    const int srow = tid >> 3;        // 0..31
    const int scol = (tid & 7) * 8;   // ushort offset

    for (int k0 = 0; k0 < K; k0 += 64) {
        __syncthreads();
        #pragma unroll
        for (int c = 0; c < 4; ++c) {
            gload16(A  + (size_t)(bm + c * 32 + srow) * K + k0 + scol,
                    (char*)As + c * 4096 + wv * 1024);
            gload16(Bt + (size_t)(bn + c * 32 + srow) * K + k0 + scol,
                    (char*)Bs + c * 4096 + wv * 1024);
        }
        __syncthreads();
        #pragma unroll
        for (int kk = 0; kk < 2; ++kk) {
            bf16x8 af[4], bfr[4];
            #pragma unroll
            for (int m = 0; m < 4; ++m)
                af[m] = *(const bf16x8*)(As + (wr + m * 16 + l15) * 64 + kk * 32 + g * 8);
            #pragma unroll
            for (int n = 0; n < 4; ++n)
                bfr[n] = *(const bf16x8*)(Bs + (wc + n * 16 + l15) * 64 + kk * 32 + g * 8);
            #pragma unroll
            for (int m = 0; m < 4; ++m)
                #pragma unroll
                for (int n = 0; n < 4; ++n)
                    acc[m][n] = __builtin_amdgcn_mfma_f32_16x16x32_bf16(af[m], bfr[n], acc[m][n], 0, 0, 0);
        }
    }

    #pragma unroll
    for (int m = 0; m < 4; ++m) {
        const int row0 = bm + wr + m * 16 + g * 4;
        #pragma unroll
        for (int n = 0; n < 4; ++n) {
            const int col = bn + wc + n * 16 + l15;
            const float bb = bias[col];
            #pragma unroll
            for (int r = 0; r < 4; ++r) {
                float v = acc[m][n][r] + bb;
                if (MODE == 0) {
                    v += res[(size_t)(row0 + r) * N + col];
                    ((float*)Cout)[(size_t)(row0 + r) * N + col] = v;
                } else if (MODE == 1) {
                    ((unsigned short*)Cout)[(size_t)(row0 + r) * N + col] = f2bf(v);
                } else {
                    float gv = 0.5f * v * (1.0f + erff(v * 0.70710678118654752f));
                    ((unsigned short*)Cout)[(size_t)(row0 + r) * N + col] = f2bf(gv);
                }
            }
        }
    }
}

// ---------------- MFMA flash attention (sliding window) ----------------
// grid (S/64, H), block 256 = 4 waves, each wave owns 16 query rows.
__global__ __launch_bounds__(256) void attn_mfma(const unsigned short* __restrict__ qkv,
                                                 const int* __restrict__ msk,
                                                 unsigned short* __restrict__ aout) {
    __shared__ unsigned short Ks[64 * 64];
    __shared__ unsigned short Vt[64 * 64];
    __shared__ unsigned short Ps[4][16 * 64];
    const int tid = threadIdx.x;
    const int wv = tid >> 6, lane = tid & 63;
    const int l15 = lane & 15, g = lane >> 4;
    const int h = blockIdx.y;
    const int q0 = blockIdx.x * 64;

    const int qrow = q0 + wv * 16 + l15;
    bf16x8 qf[2];
    #pragma unroll
    for (int kk = 0; kk < 2; ++kk)
        qf[kk] = *(const bf16x8*)(qkv + (size_t)qrow * QKVN + h * 64 + kk * 32 + g * 8);

    f32x4 o[4];
    #pragma unroll
    for (int n = 0; n < 4; ++n)
        #pragma unroll
        for (int e = 0; e < 4; ++e) o[n][e] = 0.f;
    float mst[4] = {-3e38f, -3e38f, -3e38f, -3e38f};
    float lst[4] = {0.f, 0.f, 0.f, 0.f};

    const int srow = tid >> 3;
    const int scol = (tid & 7) * 8;

    for (int c = 0; c < 9; ++c) {
        const int kc = q0 - 256 + c * 64;
        __syncthreads();
        #pragma unroll
        for (int cc = 0; cc < 2; ++cc) {
            int krow = kc + cc * 32 + srow;
            krow = min(max(krow, 0), S_LEN - 1);
            gload16(qkv + (size_t)krow * QKVN + DMODEL + h * 64 + scol,
                    (char*)Ks + cc * 4096 + wv * 1024);
        }
        #pragma unroll
        for (int cc = 0; cc < 2; ++cc) {
            int key = cc * 32 + srow;
            int vrow = min(max(kc + key, 0), S_LEN - 1);
            u16x8 vvv = *(const u16x8*)(qkv + (size_t)vrow * QKVN + 2 * DMODEL + h * 64 + scol);
            #pragma unroll
            for (int j = 0; j < 8; ++j)
                Vt[(scol + j) * 64 + key] = vvv[j];
        }
        __syncthreads();

        f32x4 s[4];
        #pragma unroll
        for (int n = 0; n < 4; ++n)
            #pragma unroll
            for (int e = 0; e < 4; ++e) s[n][e] = 0.f;
        #pragma unroll
        for (int kk = 0; kk < 2; ++kk) {
            #pragma unroll
            for (int n = 0; n < 4; ++n) {
                bf16x8 kf = *(const bf16x8*)(Ks + (n * 16 + l15) * 64 + kk * 32 + g * 8);
                s[n] = __builtin_amdgcn_mfma_f32_16x16x32_bf16(qf[kk], kf, s[n], 0, 0, 0);
            }
        }

        float pv[4][4];
        const int qbase = q0 + wv * 16 + g * 4;
        #pragma unroll
        for (int n = 0; n < 4; ++n) {
            const int key = kc + n * 16 + l15;
            const bool kin = (key >= 0) && (key < S_LEN);
            const int mv = kin ? msk[key] : 0;
            #pragma unroll
            for (int r = 0; r < 4; ++r) {
                const int qa = qbase + r;
                const bool valid = (mv != 0) && (abs(key - qa) <= WIN);
                pv[n][r] = valid ? s[n][r] * 0.125f : -1e9f;
            }
        }
        float scold[4];
        #pragma unroll
        for (int r = 0; r < 4; ++r) {
            float mx = fmaxf(fmaxf(pv[0][r], pv[1][r]), fmaxf(pv[2][r], pv[3][r]));
            mx = fmaxf(mx, __shfl_xor(mx, 1));
            mx = fmaxf(mx, __shfl_xor(mx, 2));
            mx = fmaxf(mx, __shfl_xor(mx, 4));
            mx = fmaxf(mx, __shfl_xor(mx, 8));
            const float nm = fmaxf(mst[r], mx);
            scold[r] = expf(mst[r] - nm);
            float sum = 0.f;
            #pragma unroll
            for (int n = 0; n < 4; ++n) { pv[n][r] = expf(pv[n][r] - nm); sum += pv[n][r]; }
            sum += __shfl_xor(sum, 1); sum += __shfl_xor(sum, 2);
            sum += __shfl_xor(sum, 4); sum += __shfl_xor(sum, 8);
            lst[r] = lst[r] * scold[r] + sum;
            mst[r] = nm;
        }
        #pragma unroll
        for (int n = 0; n < 4; ++n)
            #pragma unroll
            for (int r = 0; r < 4; ++r)
                o[n][r] *= scold[r];

        #pragma unroll
        for (int n = 0; n < 4; ++n)
            #pragma unroll
            for (int r = 0; r < 4; ++r)
                Ps[wv][(g * 4 + r) * 64 + n * 16 + l15] = f2bf(pv[n][r]);

        #pragma unroll
        for (int kk = 0; kk < 2; ++kk) {
            bf16x8 pf = *(const bf16x8*)(Ps[wv] + l15 * 64 + kk * 32 + g * 8);
            #pragma unroll
            for (int nd = 0; nd < 4; ++nd) {
                bf16x8 vf = *(const bf16x8*)(Vt + (nd * 16 + l15) * 64 + kk * 32 + g * 8);
                o[nd] = __builtin_amdgcn_mfma_f32_16x16x32_bf16(pf, vf, o[nd], 0, 0, 0);
            }
        }
    }

    #pragma unroll
    for (int r = 0; r < 4; ++r) {
        const float inv = 1.0f / lst[r];
        const int qa = q0 + wv * 16 + g * 4 + r;
        #pragma unroll
        for (int nd = 0; nd < 4; ++nd)
            aout[(size_t)qa * DMODEL + h * 64 + nd * 16 + l15] = f2bf(o[nd][r] * inv);
    }
}

// ---------------- Head MLP (parallelized) ----------------
// head1: 8 blocks x 256 threads; block b computes z1[b*64 .. b*64+64)
__global__ __launch_bounds__(256) void head1_kernel(const int* __restrict__ ids,
                                                    const float* __restrict__ x,
                                                    const float* __restrict__ w1,
                                                    const float* __restrict__ b1,
                                                    float* __restrict__ z1) {
    const int tid = threadIdx.x;
    __shared__ int sred[256];
    int loc = -1;
    for (int i = tid; i < S_LEN; i += 256)
        if (ids[i] == 2) loc = i;
    sred[tid] = loc;
    __syncthreads();
    for (int s2 = 128; s2; s2 >>= 1) {
        if (tid < s2) sred[tid] = max(sred[tid], sred[tid + s2]);
        __syncthreads();
    }
    const int sep = sred[0] < 0 ? (S_LEN - 1) : sred[0];

    __shared__ float emb[DMODEL];
    for (int d = tid; d < DMODEL; d += 256) emb[d] = x[(size_t)sep * DMODEL + d];
    __syncthreads();

    const int o = blockIdx.x * 64 + (tid & 63);
    const int chunk = tid >> 6;              // 0..3, 192 d's each
    float s = 0.f;
    const int d0 = chunk * 192;
    for (int d = d0; d < d0 + 192; ++d)
        s += emb[d] * w1[(size_t)d * 512 + o];
    __shared__ float part[4][64];
    part[chunk][tid & 63] = s;
    __syncthreads();
    if (chunk == 0) {
        float v = part[0][tid] + part[1][tid] + part[2][tid] + part[3][tid] + b1[o];
        z1[o] = fmaxf(v, 0.f);
    }
}

// head2: single block; z2 = relu(z1@w2+b2); out = tanh(z2.w3 + b3)
__global__ __launch_bounds__(256) void head2_kernel(const float* __restrict__ z1,
                                                    const float* __restrict__ w2,
                                                    const float* __restrict__ b2,
                                                    const float* __restrict__ w3,
                                                    const float* __restrict__ b3,
                                                    float* __restrict__ out) {
    const int tid = threadIdx.x;
    __shared__ float z1s[512];
    for (int i = tid; i < 512; i += 256) z1s[i] = z1[i];
    __syncthreads();
    float s = b2[tid];
    for (int d = 0; d < 512; ++d) s += z1s[d] * w2[(size_t)d * 256 + tid];
    float z2 = fmaxf(s, 0.f);
    __shared__ float fred[256];
    fred[tid] = z2 * w3[tid];
    __syncthreads();
    for (int s2 = 128; s2; s2 >>= 1) {
        if (tid < s2) fred[tid] += fred[tid + s2];
        __syncthreads();
    }
    if (tid == 0) out[0] = tanhf(fred[0] + b3[0]);
}

// ---------------- launch ----------------

extern "C" void kernel_launch(void* const* d_in, const int* in_sizes, int n_in,
                              void* d_out, int out_size, void* d_ws, size_t ws_size,
                              hipStream_t stream) {
    const int*   ids      = (const int*)d_in[0];
    const int*   amask    = (const int*)d_in[1];
    const float* word_emb = (const float*)d_in[2];
    const float* pos_emb  = (const float*)d_in[3];
    const float* emb_s    = (const float*)d_in[4];
    const float* emb_b    = (const float*)d_in[5];
    const float* Wq = (const float*)d_in[6];
    const float* bq = (const float*)d_in[7];
    const float* Wk = (const float*)d_in[8];
    const float* bk = (const float*)d_in[9];
    const float* Wv = (const float*)d_in[10];
    const float* bv = (const float*)d_in[11];
    const float* Wo = (const float*)d_in[12];
    const float* bo = (const float*)d_in[13];
    const float* l1s = (const float*)d_in[14];
    const float* l1b = (const float*)d_in[15];
    const float* W1 = (const float*)d_in[16];
    const float* b1 = (const float*)d_in[17];
    const float* W2 = (const float*)d_in[18];
    const float* b2 = (const float*)d_in[19];
    const float* l2s = (const float*)d_in[20];
    const float* l2b = (const float*)d_in[21];
    const float* h1w = (const float*)d_in[22];
    const float* h1b = (const float*)d_in[23];
    const float* h2w = (const float*)d_in[24];
    const float* h2b = (const float*)d_in[25];
    const float* h3w = (const float*)d_in[26];
    const float* h3b = (const float*)d_in[27];

    char* ws = (char*)d_ws;
    float* x          = (float*)(ws);                              // 12.58 MB
    float* t          = (float*)(ws + 12582912);                   // 12.58 MB
    unsigned short* xb   = (unsigned short*)(ws + 25165824);       // 6.29 MB
    unsigned short* qkv  = (unsigned short*)(ws + 31457280);       // 18.87 MB
    unsigned short* a    = (unsigned short*)(ws + 50331648);       // 6.29 MB
    unsigned short* hb   = (unsigned short*)(ws + 56623104);       // 25.17 MB
    unsigned short* WqkvT= (unsigned short*)(ws + 81788928);       // 3.54 MB
    unsigned short* WoT  = (unsigned short*)(ws + 85327872);       // 1.18 MB
    unsigned short* W1T  = (unsigned short*)(ws + 86507520);       // 4.72 MB
    unsigned short* W2T  = (unsigned short*)(ws + 91226112);       // 4.72 MB
    float* biascat       = (float*)(ws + 95944704);                // 0.11 MB
    float* z1ws          = (float*)(ws + 96055296);                // 2 KB

    bias_concat<<<NLAYER, 256, 0, stream>>>(bq, bk, bv, biascat);
    embed_ln_kernel<<<S_LEN, 256, 0, stream>>>(ids, word_emb, pos_emb, emb_s, emb_b, x, xb);

    const size_t dd = (size_t)DMODEL * DMODEL;
    const size_t df = (size_t)DMODEL * FFDIM;

    for (int l = 0; l < NLAYER; ++l) {
        transpose_all<<<6912, 256, 0, stream>>>(Wq + l * dd, Wk + l * dd, Wv + l * dd, Wo + l * dd,
                                                W1 + l * df, W2 + l * df,
                                                WqkvT, WqkvT + dd, WqkvT + 2 * dd, WoT, W1T, W2T);

        mfma_gemm<1><<<dim3(32, 18), 256, 0, stream>>>(xb, WqkvT, biascat + (size_t)l * QKVN,
                                                       nullptr, qkv, S_LEN, QKVN, DMODEL);
        attn_mfma<<<dim3(S_LEN / 64, NHEAD), 256, 0, stream>>>(qkv, amask, a);

        mfma_gemm<0><<<dim3(32, 6), 256, 0, stream>>>(a, WoT, bo + (size_t)l * DMODEL,
                                                      x, t, S_LEN, DMODEL, DMODEL);
        ln_kernel<<<S_LEN, 256, 0, stream>>>(t, l1s + (size_t)l * DMODEL, l1b + (size_t)l * DMODEL, x, xb);

        mfma_gemm<2><<<dim3(32, 24), 256, 0, stream>>>(xb, W1T, b1 + (size_t)l * FFDIM,
                                                       nullptr, hb, S_LEN, FFDIM, DMODEL);
        mfma_gemm<0><<<dim3(32, 6), 256, 0, stream>>>(hb, W2T, b2 + (size_t)l * DMODEL,
                                                      x, t, S_LEN, DMODEL, FFDIM);
        ln_kernel<<<S_LEN, 256, 0, stream>>>(t, l2s + (size_t)l * DMODEL, l2b + (size_t)l * DMODEL, x, xb);
    }

    head1_kernel<<<8, 256, 0, stream>>>(ids, x, h1w, h1b, z1ws);
    head2_kernel<<<1, 256, 0, stream>>>(z1ws, h2w, h2b, h3w, h3b, (float*)d_out);
}

// Round 4
// 2748.565 us; speedup vs baseline: 9.9536x; 1.1306x over previous
//
#include <hip/hip_runtime.h>
#include <math.h>

#define S_LEN 4096
#define DMODEL 768
#define NHEAD 12
#define DHEAD 64
#define FFDIM 3072
#define NLAYER 12
#define WIN 256
#define QKVN 2304

typedef __bf16 bf16x8 __attribute__((ext_vector_type(8)));
typedef unsigned short u16x8 __attribute__((ext_vector_type(8)));
typedef float f32x4 __attribute__((ext_vector_type(4)));

__device__ inline unsigned short f2bf(float f) {
    unsigned int u = __float_as_uint(f);
    u += 0x7fff + ((u >> 16) & 1);
    return (unsigned short)(u >> 16);
}

__device__ inline void gload16(const void* g, void* l) {
    __builtin_amdgcn_global_load_lds((const __attribute__((address_space(1))) void*)g,
                                     (__attribute__((address_space(3))) void*)l, 16, 0, 0);
}

// ---------------- LayerNorm ----------------

__device__ inline void block_reduce2(float& sum, float& sq) {
    #pragma unroll
    for (int off = 32; off; off >>= 1) {
        sum += __shfl_xor(sum, off);
        sq  += __shfl_xor(sq, off);
    }
    __shared__ float red[8];
    int wid = threadIdx.x >> 6, lane = threadIdx.x & 63;
    if (lane == 0) { red[wid] = sum; red[wid + 4] = sq; }
    __syncthreads();
    sum = red[0] + red[1] + red[2] + red[3];
    sq  = red[4] + red[5] + red[6] + red[7];
    __syncthreads();
}

__global__ __launch_bounds__(256) void ln_kernel(const float* __restrict__ in,
                                                 const float* __restrict__ s,
                                                 const float* __restrict__ b,
                                                 float* __restrict__ out,
                                                 unsigned short* __restrict__ outb) {
    int row = blockIdx.x, tid = threadIdx.x;
    const float* p = in + (size_t)row * DMODEL;
    float v0 = p[tid], v1 = p[tid + 256], v2 = p[tid + 512];
    float sum = v0 + v1 + v2;
    float sq  = v0 * v0 + v1 * v1 + v2 * v2;
    block_reduce2(sum, sq);
    float mu = sum * (1.0f / DMODEL);
    float var = sq * (1.0f / DMODEL) - mu * mu;
    float rs = rsqrtf(var + 1e-5f);
    float* o = out + (size_t)row * DMODEL;
    unsigned short* ob = outb + (size_t)row * DMODEL;
    float r0 = (v0 - mu) * rs * s[tid]       + b[tid];
    float r1 = (v1 - mu) * rs * s[tid + 256] + b[tid + 256];
    float r2 = (v2 - mu) * rs * s[tid + 512] + b[tid + 512];
    o[tid] = r0; o[tid + 256] = r1; o[tid + 512] = r2;
    ob[tid] = f2bf(r0); ob[tid + 256] = f2bf(r1); ob[tid + 512] = f2bf(r2);
}

__global__ __launch_bounds__(256) void embed_ln_kernel(const int* __restrict__ ids,
                                                       const float* __restrict__ wemb,
                                                       const float* __restrict__ pemb,
                                                       const float* __restrict__ s,
                                                       const float* __restrict__ b,
                                                       float* __restrict__ out,
                                                       unsigned short* __restrict__ outb) {
    int row = blockIdx.x, tid = threadIdx.x;
    int id = ids[row];
    const float* wp = wemb + (size_t)id * DMODEL;
    const float* pp = pemb + (size_t)(row + 2) * DMODEL;
    float v0 = wp[tid] + pp[tid];
    float v1 = wp[tid + 256] + pp[tid + 256];
    float v2 = wp[tid + 512] + pp[tid + 512];
    float sum = v0 + v1 + v2;
    float sq  = v0 * v0 + v1 * v1 + v2 * v2;
    block_reduce2(sum, sq);
    float mu = sum * (1.0f / DMODEL);
    float var = sq * (1.0f / DMODEL) - mu * mu;
    float rs = rsqrtf(var + 1e-5f);
    float* o = out + (size_t)row * DMODEL;
    unsigned short* ob = outb + (size_t)row * DMODEL;
    float r0 = (v0 - mu) * rs * s[tid]       + b[tid];
    float r1 = (v1 - mu) * rs * s[tid + 256] + b[tid + 256];
    float r2 = (v2 - mu) * rs * s[tid + 512] + b[tid + 512];
    o[tid] = r0; o[tid + 256] = r1; o[tid + 512] = r2;
    ob[tid] = f2bf(r0); ob[tid + 256] = f2bf(r1); ob[tid + 512] = f2bf(r2);
}

// ---------------- merged per-layer weight transpose + cvt ----------------
__global__ __launch_bounds__(256) void transpose_all(const float* __restrict__ wq,
                                                     const float* __restrict__ wk,
                                                     const float* __restrict__ wv,
                                                     const float* __restrict__ wo,
                                                     const float* __restrict__ w1,
                                                     const float* __restrict__ w2,
                                                     unsigned short* __restrict__ dq,
                                                     unsigned short* __restrict__ dk,
                                                     unsigned short* __restrict__ dv,
                                                     unsigned short* __restrict__ dwo,
                                                     unsigned short* __restrict__ d1,
                                                     unsigned short* __restrict__ d2) {
    const int id = blockIdx.x;
    const float* src; unsigned short* dst; int C, R, bx, by;
    if (id < 2304) {
        const int m = id / 576, t2 = id % 576;
        src = (m == 0) ? wq : (m == 1) ? wk : (m == 2) ? wv : wo;
        dst = (m == 0) ? dq : (m == 1) ? dk : (m == 2) ? dv : dwo;
        R = 768; C = 768; bx = (t2 % 24) * 32; by = (t2 / 24) * 32;
    } else if (id < 4608) {
        const int t2 = id - 2304;
        src = w1; dst = d1; R = 768; C = 3072;
        bx = (t2 % 96) * 32; by = (t2 / 96) * 32;
    } else {
        const int t2 = id - 4608;
        src = w2; dst = d2; R = 3072; C = 768;
        bx = (t2 % 24) * 32; by = (t2 / 24) * 32;
    }
    __shared__ float tile[32][33];
    const int tx = threadIdx.x & 31, ty = threadIdx.x >> 5;
    #pragma unroll
    for (int k = 0; k < 4; ++k)
        tile[ty + k * 8][tx] = src[(size_t)(by + ty + k * 8) * C + bx + tx];
    __syncthreads();
    #pragma unroll
    for (int k = 0; k < 4; ++k)
        dst[(size_t)(bx + ty + k * 8) * R + by + tx] = f2bf(tile[tx][ty + k * 8]);
}

__global__ __launch_bounds__(256) void bias_concat(const float* __restrict__ bq,
                                                   const float* __restrict__ bk,
                                                   const float* __restrict__ bv,
                                                   float* __restrict__ out) {
    int l = blockIdx.x, t = threadIdx.x;
    for (int i = t; i < DMODEL; i += 256) {
        out[(size_t)l * QKVN + i]              = bq[(size_t)l * DMODEL + i];
        out[(size_t)l * QKVN + DMODEL + i]     = bk[(size_t)l * DMODEL + i];
        out[(size_t)l * QKVN + 2 * DMODEL + i] = bv[(size_t)l * DMODEL + i];
    }
}

// ---------------- bf16 MFMA GEMM ----------------
// C[M][N] = A[M][K] @ Bt[N][K]^T + bias (+res)(+gelu)
// MODE 0: fp32 out = acc+bias+res; 1: bf16 out = acc+bias; 2: bf16 out = gelu(acc+bias)
// BN = 128 (4 waves in 2x2) or 64 (4 waves stacked in M; grid doubles for N=768)
template<int MODE, int BN>
__global__ __launch_bounds__(256) void mfma_gemm(const unsigned short* __restrict__ A,
                                                 const unsigned short* __restrict__ Bt,
                                                 const float* __restrict__ bias,
                                                 const float* __restrict__ res,
                                                 void* __restrict__ Cout,
                                                 int M, int N, int K) {
    constexpr int MR = (BN == 128) ? 4 : 2;   // m-fragments per wave
    __shared__ unsigned short As[128 * 64];
    __shared__ unsigned short Bs[BN * 64];
    const int tid = threadIdx.x;
    const int wv = tid >> 6, lane = tid & 63;
    const int bm = blockIdx.x * 128, bn = blockIdx.y * BN;
    const int wr = (BN == 128) ? (wv >> 1) * 64 : wv * 32;
    const int wc = (BN == 128) ? (wv & 1) * 64 : 0;
    const int l15 = lane & 15, g = lane >> 4;

    f32x4 acc[MR][4];
    #pragma unroll
    for (int m = 0; m < MR; ++m)
        #pragma unroll
        for (int n = 0; n < 4; ++n)
            #pragma unroll
            for (int e = 0; e < 4; ++e) acc[m][n][e] = 0.f;

    const int srow = tid >> 3;        // 0..31
    const int scol = (tid & 7) * 8;   // ushort offset

    for (int k0 = 0; k0 < K; k0 += 64) {
        __syncthreads();
        #pragma unroll
        for (int c = 0; c < 4; ++c)
            gload16(A + (size_t)(bm + c * 32 + srow) * K + k0 + scol,
                    (char*)As + c * 4096 + wv * 1024);
        #pragma unroll
        for (int c = 0; c < BN / 32; ++c)
            gload16(Bt + (size_t)(bn + c * 32 + srow) * K + k0 + scol,
                    (char*)Bs + c * 4096 + wv * 1024);
        __syncthreads();
        #pragma unroll
        for (int kk = 0; kk < 2; ++kk) {
            bf16x8 af[MR], bfr[4];
            #pragma unroll
            for (int m = 0; m < MR; ++m)
                af[m] = *(const bf16x8*)(As + (wr + m * 16 + l15) * 64 + kk * 32 + g * 8);
            #pragma unroll
            for (int n = 0; n < 4; ++n)
                bfr[n] = *(const bf16x8*)(Bs + (wc + n * 16 + l15) * 64 + kk * 32 + g * 8);
            #pragma unroll
            for (int m = 0; m < MR; ++m)
                #pragma unroll
                for (int n = 0; n < 4; ++n)
                    acc[m][n] = __builtin_amdgcn_mfma_f32_16x16x32_bf16(af[m], bfr[n], acc[m][n], 0, 0, 0);
        }
    }

    #pragma unroll
    for (int m = 0; m < MR; ++m) {
        const int row0 = bm + wr + m * 16 + g * 4;
        #pragma unroll
        for (int n = 0; n < 4; ++n) {
            const int col = bn + wc + n * 16 + l15;
            const float bb = bias[col];
            #pragma unroll
            for (int r = 0; r < 4; ++r) {
                float v = acc[m][n][r] + bb;
                if (MODE == 0) {
                    v += res[(size_t)(row0 + r) * N + col];
                    ((float*)Cout)[(size_t)(row0 + r) * N + col] = v;
                } else if (MODE == 1) {
                    ((unsigned short*)Cout)[(size_t)(row0 + r) * N + col] = f2bf(v);
                } else {
                    float gv = 0.5f * v * (1.0f + erff(v * 0.70710678118654752f));
                    ((unsigned short*)Cout)[(size_t)(row0 + r) * N + col] = f2bf(gv);
                }
            }
        }
    }
}

// ---------------- MFMA flash attention (sliding window) ----------------
// grid (S/64, H), block 256 = 4 waves, each wave owns 16 query rows.
// All LDS tiles XOR-swizzled: element [row][col] stored at col ^ f(row)
// (K, P: f = (row&7)<<3 applied to d/key col; Vt: f = (((d>>3)^d)&7)<<3 on key).
__global__ __launch_bounds__(256) void attn_mfma(const unsigned short* __restrict__ qkv,
                                                 const int* __restrict__ msk,
                                                 unsigned short* __restrict__ aout) {
    __shared__ unsigned short Ks[64 * 64];
    __shared__ unsigned short Vt[64 * 64];
    __shared__ unsigned short Ps[4][16 * 64];
    const int tid = threadIdx.x;
    const int wv = tid >> 6, lane = tid & 63;
    const int l15 = lane & 15, g = lane >> 4;
    const int h = blockIdx.y;
    const int q0 = blockIdx.x * 64;

    const int qrow = q0 + wv * 16 + l15;
    bf16x8 qf[2];
    #pragma unroll
    for (int kk = 0; kk < 2; ++kk)
        qf[kk] = *(const bf16x8*)(qkv + (size_t)qrow * QKVN + h * 64 + kk * 32 + g * 8);

    f32x4 o[4];
    #pragma unroll
    for (int n = 0; n < 4; ++n)
        #pragma unroll
        for (int e = 0; e < 4; ++e) o[n][e] = 0.f;
    float mst[4] = {-3e38f, -3e38f, -3e38f, -3e38f};
    float lst[4] = {0.f, 0.f, 0.f, 0.f};

    const int srow = tid >> 3;        // local key slot within 32-row chunk
    const int scol = (tid & 7) * 8;   // d offset (8 bf16)
    const int xr  = (l15 & 7) << 3;   // read-side XOR for K and P rows

    for (int c = 0; c < 9; ++c) {
        const int kc = q0 - 256 + c * 64;
        __syncthreads();
        // K: linear LDS dest, pre-swizzled global source column (rule: both-sides)
        #pragma unroll
        for (int cc = 0; cc < 2; ++cc) {
            const int r = cc * 32 + srow;                 // local key slot 0..63
            int krow = min(max(kc + r, 0), S_LEN - 1);
            gload16(qkv + (size_t)krow * QKVN + DMODEL + h * 64 + (scol ^ ((r & 7) << 3)),
                    (char*)Ks + cc * 4096 + wv * 1024);
        }
        // V: reg-staged transpose into swizzled Vt[d][key ^ f(d)]
        #pragma unroll
        for (int cc = 0; cc < 2; ++cc) {
            const int r = cc * 32 + srow;
            int vrow = min(max(kc + r, 0), S_LEN - 1);
            u16x8 vvv = *(const u16x8*)(qkv + (size_t)vrow * QKVN + 2 * DMODEL + h * 64 + scol);
            const int xb = (scol >> 3) & 7;
            #pragma unroll
            for (int j = 0; j < 8; ++j)
                Vt[(scol + j) * 64 + (r ^ ((xb ^ j) << 3))] = vvv[j];
        }
        __syncthreads();

        // S = Q K^T
        f32x4 s[4];
        #pragma unroll
        for (int n = 0; n < 4; ++n)
            #pragma unroll
            for (int e = 0; e < 4; ++e) s[n][e] = 0.f;
        #pragma unroll
        for (int kk = 0; kk < 2; ++kk) {
            #pragma unroll
            for (int n = 0; n < 4; ++n) {
                bf16x8 kf = *(const bf16x8*)(Ks + (n * 16 + l15) * 64 + ((kk * 32 + g * 8) ^ xr));
                s[n] = __builtin_amdgcn_mfma_f32_16x16x32_bf16(qf[kk], kf, s[n], 0, 0, 0);
            }
        }

        // mask + online softmax
        float pv[4][4];
        const int qbase = q0 + wv * 16 + g * 4;
        #pragma unroll
        for (int n = 0; n < 4; ++n) {
            const int key = kc + n * 16 + l15;
            const bool kin = (key >= 0) && (key < S_LEN);
            const int mv = kin ? msk[key] : 0;
            #pragma unroll
            for (int r = 0; r < 4; ++r) {
                const int qa = qbase + r;
                const bool valid = (mv != 0) && (abs(key - qa) <= WIN);
                pv[n][r] = valid ? s[n][r] * 0.125f : -1e9f;
            }
        }
        float scold[4];
        #pragma unroll
        for (int r = 0; r < 4; ++r) {
            float mx = fmaxf(fmaxf(pv[0][r], pv[1][r]), fmaxf(pv[2][r], pv[3][r]));
            mx = fmaxf(mx, __shfl_xor(mx, 1));
            mx = fmaxf(mx, __shfl_xor(mx, 2));
            mx = fmaxf(mx, __shfl_xor(mx, 4));
            mx = fmaxf(mx, __shfl_xor(mx, 8));
            const float nm = fmaxf(mst[r], mx);
            scold[r] = expf(mst[r] - nm);
            float sum = 0.f;
            #pragma unroll
            for (int n = 0; n < 4; ++n) { pv[n][r] = expf(pv[n][r] - nm); sum += pv[n][r]; }
            sum += __shfl_xor(sum, 1); sum += __shfl_xor(sum, 2);
            sum += __shfl_xor(sum, 4); sum += __shfl_xor(sum, 8);
            lst[r] = lst[r] * scold[r] + sum;
            mst[r] = nm;
        }
        #pragma unroll
        for (int n = 0; n < 4; ++n)
            #pragma unroll
            for (int r = 0; r < 4; ++r)
                o[n][r] *= scold[r];

        // P -> LDS (swizzled by local q row)
        #pragma unroll
        for (int n = 0; n < 4; ++n)
            #pragma unroll
            for (int r = 0; r < 4; ++r) {
                const int ql = g * 4 + r;
                Ps[wv][ql * 64 + ((n * 16 + l15) ^ ((ql & 7) << 3))] = f2bf(pv[n][r]);
            }

        // O += P @ V
        #pragma unroll
        for (int kk = 0; kk < 2; ++kk) {
            bf16x8 pf = *(const bf16x8*)(Ps[wv] + l15 * 64 + ((kk * 32 + g * 8) ^ xr));
            #pragma unroll
            for (int nd = 0; nd < 4; ++nd) {
                const int d = nd * 16 + l15;
                const int xv = (((nd * 2 + (l15 >> 3)) & 7) ^ (l15 & 7)) << 3;
                bf16x8 vf = *(const bf16x8*)(Vt + d * 64 + ((kk * 32 + g * 8) ^ xv));
                o[nd] = __builtin_amdgcn_mfma_f32_16x16x32_bf16(pf, vf, o[nd], 0, 0, 0);
            }
        }
    }

    #pragma unroll
    for (int r = 0; r < 4; ++r) {
        const float inv = 1.0f / lst[r];
        const int qa = q0 + wv * 16 + g * 4 + r;
        #pragma unroll
        for (int nd = 0; nd < 4; ++nd)
            aout[(size_t)qa * DMODEL + h * 64 + nd * 16 + l15] = f2bf(o[nd][r] * inv);
    }
}

// ---------------- Head MLP (parallelized) ----------------
__global__ __launch_bounds__(256) void head1_kernel(const int* __restrict__ ids,
                                                    const float* __restrict__ x,
                                                    const float* __restrict__ w1,
                                                    const float* __restrict__ b1,
                                                    float* __restrict__ z1) {
    const int tid = threadIdx.x;
    __shared__ int sred[256];
    int loc = -1;
    for (int i = tid; i < S_LEN; i += 256)
        if (ids[i] == 2) loc = i;
    sred[tid] = loc;
    __syncthreads();
    for (int s2 = 128; s2; s2 >>= 1) {
        if (tid < s2) sred[tid] = max(sred[tid], sred[tid + s2]);
        __syncthreads();
    }
    const int sep = sred[0] < 0 ? (S_LEN - 1) : sred[0];

    __shared__ float emb[DMODEL];
    for (int d = tid; d < DMODEL; d += 256) emb[d] = x[(size_t)sep * DMODEL + d];
    __syncthreads();

    const int o = blockIdx.x * 64 + (tid & 63);
    const int chunk = tid >> 6;
    float s = 0.f;
    const int d0 = chunk * 192;
    for (int d = d0; d < d0 + 192; ++d)
        s += emb[d] * w1[(size_t)d * 512 + o];
    __shared__ float part[4][64];
    part[chunk][tid & 63] = s;
    __syncthreads();
    if (chunk == 0) {
        float v = part[0][tid] + part[1][tid] + part[2][tid] + part[3][tid] + b1[o];
        z1[o] = fmaxf(v, 0.f);
    }
}

__global__ __launch_bounds__(256) void head2_kernel(const float* __restrict__ z1,
                                                    const float* __restrict__ w2,
                                                    const float* __restrict__ b2,
                                                    const float* __restrict__ w3,
                                                    const float* __restrict__ b3,
                                                    float* __restrict__ out) {
    const int tid = threadIdx.x;
    __shared__ float z1s[512];
    for (int i = tid; i < 512; i += 256) z1s[i] = z1[i];
    __syncthreads();
    float s = b2[tid];
    for (int d = 0; d < 512; ++d) s += z1s[d] * w2[(size_t)d * 256 + tid];
    float z2 = fmaxf(s, 0.f);
    __shared__ float fred[256];
    fred[tid] = z2 * w3[tid];
    __syncthreads();
    for (int s2 = 128; s2; s2 >>= 1) {
        if (tid < s2) fred[tid] += fred[tid + s2];
        __syncthreads();
    }
    if (tid == 0) out[0] = tanhf(fred[0] + b3[0]);
}

// ---------------- launch ----------------

extern "C" void kernel_launch(void* const* d_in, const int* in_sizes, int n_in,
                              void* d_out, int out_size, void* d_ws, size_t ws_size,
                              hipStream_t stream) {
    const int*   ids      = (const int*)d_in[0];
    const int*   amask    = (const int*)d_in[1];
    const float* word_emb = (const float*)d_in[2];
    const float* pos_emb  = (const float*)d_in[3];
    const float* emb_s    = (const float*)d_in[4];
    const float* emb_b    = (const float*)d_in[5];
    const float* Wq = (const float*)d_in[6];
    const float* bq = (const float*)d_in[7];
    const float* Wk = (const float*)d_in[8];
    const float* bk = (const float*)d_in[9];
    const float* Wv = (const float*)d_in[10];
    const float* bv = (const float*)d_in[11];
    const float* Wo = (const float*)d_in[12];
    const float* bo = (const float*)d_in[13];
    const float* l1s = (const float*)d_in[14];
    const float* l1b = (const float*)d_in[15];
    const float* W1 = (const float*)d_in[16];
    const float* b1 = (const float*)d_in[17];
    const float* W2 = (const float*)d_in[18];
    const float* b2 = (const float*)d_in[19];
    const float* l2s = (const float*)d_in[20];
    const float* l2b = (const float*)d_in[21];
    const float* h1w = (const float*)d_in[22];
    const float* h1b = (const float*)d_in[23];
    const float* h2w = (const float*)d_in[24];
    const float* h2b = (const float*)d_in[25];
    const float* h3w = (const float*)d_in[26];
    const float* h3b = (const float*)d_in[27];

    char* ws = (char*)d_ws;
    float* x          = (float*)(ws);                              // 12.58 MB
    float* t          = (float*)(ws + 12582912);                   // 12.58 MB
    unsigned short* xb   = (unsigned short*)(ws + 25165824);       // 6.29 MB
    unsigned short* qkv  = (unsigned short*)(ws + 31457280);       // 18.87 MB
    unsigned short* a    = (unsigned short*)(ws + 50331648);       // 6.29 MB
    unsigned short* hb   = (unsigned short*)(ws + 56623104);       // 25.17 MB
    unsigned short* WqkvT= (unsigned short*)(ws + 81788928);       // 3.54 MB
    unsigned short* WoT  = (unsigned short*)(ws + 85327872);       // 1.18 MB
    unsigned short* W1T  = (unsigned short*)(ws + 86507520);       // 4.72 MB
    unsigned short* W2T  = (unsigned short*)(ws + 91226112);       // 4.72 MB
    float* biascat       = (float*)(ws + 95944704);                // 0.11 MB
    float* z1ws          = (float*)(ws + 96055296);                // 2 KB

    bias_concat<<<NLAYER, 256, 0, stream>>>(bq, bk, bv, biascat);
    embed_ln_kernel<<<S_LEN, 256, 0, stream>>>(ids, word_emb, pos_emb, emb_s, emb_b, x, xb);

    const size_t dd = (size_t)DMODEL * DMODEL;
    const size_t df = (size_t)DMODEL * FFDIM;

    for (int l = 0; l < NLAYER; ++l) {
        transpose_all<<<6912, 256, 0, stream>>>(Wq + l * dd, Wk + l * dd, Wv + l * dd, Wo + l * dd,
                                                W1 + l * df, W2 + l * df,
                                                WqkvT, WqkvT + dd, WqkvT + 2 * dd, WoT, W1T, W2T);

        mfma_gemm<1, 128><<<dim3(32, 18), 256, 0, stream>>>(xb, WqkvT, biascat + (size_t)l * QKVN,
                                                            nullptr, qkv, S_LEN, QKVN, DMODEL);
        attn_mfma<<<dim3(S_LEN / 64, NHEAD), 256, 0, stream>>>(qkv, amask, a);

        mfma_gemm<0, 64><<<dim3(32, 12), 256, 0, stream>>>(a, WoT, bo + (size_t)l * DMODEL,
                                                           x, t, S_LEN, DMODEL, DMODEL);
        ln_kernel<<<S_LEN, 256, 0, stream>>>(t, l1s + (size_t)l * DMODEL, l1b + (size_t)l * DMODEL, x, xb);

        mfma_gemm<2, 128><<<dim3(32, 24), 256, 0, stream>>>(xb, W1T, b1 + (size_t)l * FFDIM,
                                                            nullptr, hb, S_LEN, FFDIM, DMODEL);
        mfma_gemm<0, 64><<<dim3(32, 12), 256, 0, stream>>>(hb, W2T, b2 + (size_t)l * DMODEL,
                                                           x, t, S_LEN, DMODEL, FFDIM);
        ln_kernel<<<S_LEN, 256, 0, stream>>>(t, l2s + (size_t)l * DMODEL, l2b + (size_t)l * DMODEL, x, xb);
    }

    head1_kernel<<<8, 256, 0, stream>>>(ids, x, h1w, h1b, z1ws);
    head2_kernel<<<1, 256, 0, stream>>>(z1ws, h2w, h2b, h3w, h3b, (float*)d_out);
}